// Round 11
// baseline (192.187 us; speedup 1.0000x reference)
//
#include <hip/hip_runtime.h>
#include <hip/hip_bf16.h>
#include <hip/hip_fp8.h>

#define NNODE 50000
#define MTOT  100000   // 2*NNODE rows
#define NF    256
#define KNB   10

typedef unsigned short u16;
typedef float f32x4 __attribute__((ext_vector_type(4)));
typedef float f32x2 __attribute__((ext_vector_type(2)));
typedef short bf16x8 __attribute__((ext_vector_type(8)));

__device__ __forceinline__ u16 f2bf(float f) {
    unsigned u = __builtin_bit_cast(unsigned, f);
    unsigned r = (u + 0x7fffu + ((u >> 16) & 1u)) >> 16;
    return (u16)r;
}
__device__ __forceinline__ unsigned char f2f8(float f) {
    return (unsigned char)__hip_fp8_e4m3(f).__x;
}
__device__ __forceinline__ float f8tof(unsigned char b) {
    __hip_fp8_e4m3 h;
    h.__x = (__hip_fp8_storage_t)b;
    return (float)h;
}
template <int WORD>
__device__ __forceinline__ f32x2 cvt2_fp8(unsigned v) {
#if __has_builtin(__builtin_amdgcn_cvt_pk_f32_fp8)
    auto c = __builtin_amdgcn_cvt_pk_f32_fp8((int)v, WORD);
    f32x2 r; r.x = c[0]; r.y = c[1];
    return r;
#else
    unsigned s = WORD ? (v >> 16) : v;
    f32x2 r;
    r.x = f8tof((unsigned char)(s & 0xff));
    r.y = f8tof((unsigned char)((s >> 8) & 0xff));
    return r;
#endif
}
template <int WORD>
__device__ __forceinline__ unsigned pk_fp8(float a, float b, unsigned old) {
#if __has_builtin(__builtin_amdgcn_cvt_pk_fp8_f32)
    return (unsigned)__builtin_amdgcn_cvt_pk_fp8_f32(a, b, (int)old, WORD);
#else
    unsigned lo = (unsigned)f2f8(a) | ((unsigned)f2f8(b) << 8);
    return WORD ? ((old & 0x0000ffffu) | (lo << 16)) : ((old & 0xffff0000u) | lo);
#endif
}
__device__ __forceinline__ void gload_lds16(const void* g, void* l) {
    __builtin_amdgcn_global_load_lds(
        (const __attribute__((address_space(1))) unsigned int*)g,
        (__attribute__((address_space(3))) unsigned int*)l, 16, 0, 0);
}

// ---- kernel 1: merged cast.
//  [0,12500): Z -> bf16 Zleft + fp8 Z8
//  [12500,12756): WT bf16 [256 n][256 k] = Wr^T
//  [12756,13012): WT8 fp8 [256 n][256 k] = Wnr^T
__global__ __launch_bounds__(256) void cast_all(const float* __restrict__ Z1,
                                                const float* __restrict__ Z2,
                                                const float* __restrict__ Wr,
                                                const float* __restrict__ Wnr,
                                                u16* __restrict__ Zleft,
                                                unsigned char* __restrict__ Z8,
                                                u16* __restrict__ WT,
                                                unsigned char* __restrict__ WT8) {
    int b = blockIdx.x;
    if (b < 12500) {
        unsigned id = b * 256 + threadIdx.x;
        int m = id >> 5;
        int d = (id & 31) << 3;
        const float* src = (m < NNODE) ? (Z1 + (size_t)m * 256 + d)
                                       : (Z2 + (size_t)(m - NNODE) * 256 + d);
        float4 a = *(const float4*)src;
        float4 bb = *(const float4*)(src + 4);
        uint4 o;
        o.x = (unsigned)f2bf(a.x) | ((unsigned)f2bf(a.y) << 16);
        o.y = (unsigned)f2bf(a.z) | ((unsigned)f2bf(a.w) << 16);
        o.z = (unsigned)f2bf(bb.x) | ((unsigned)f2bf(bb.y) << 16);
        o.w = (unsigned)f2bf(bb.z) | ((unsigned)f2bf(bb.w) << 16);
        *(uint4*)(Zleft + (size_t)m * 256 + d) = o;
        uint2 o8;
        o8.x = (unsigned)f2f8(a.x) | ((unsigned)f2f8(a.y) << 8) |
               ((unsigned)f2f8(a.z) << 16) | ((unsigned)f2f8(a.w) << 24);
        o8.y = (unsigned)f2f8(bb.x) | ((unsigned)f2f8(bb.y) << 8) |
               ((unsigned)f2f8(bb.z) << 16) | ((unsigned)f2f8(bb.w) << 24);
        *(uint2*)(Z8 + (size_t)m * 256 + d) = o8;
    } else if (b < 12756) {
        int id = (b - 12500) * 256 + threadIdx.x;
        int n = id >> 8, k = id & 255;
        WT[n * 256 + k] = f2bf(Wr[(size_t)k * 256 + n]);
    } else {
        int id = (b - 12756) * 256 + threadIdx.x;
        int n = id >> 8, k = id & 255;
        WT8[n * 256 + k] = f2f8(Wnr[(size_t)k * 256 + n]);
    }
}

// ---- B staging: linear LDS dest + inverse-swizzled global source
__device__ __forceinline__ void stageBl(const u16* __restrict__ WT, u16* dst,
                                        int kt, int t) {
    // [256c][64k] bf16 = 2048 granules of 16B, 4/thread, XOR col&7
    #pragma unroll
    for (int rp = 0; rp < 4; ++rp) {
        int c = rp * 512 + t;
        int col = c >> 3, gd = c & 7;
        int gs = gd ^ (col & 7);
        gload_lds16(WT + (size_t)col * 256 + kt + gs * 8, dst + c * 8);
    }
}

// ---- consume gather packet of step s: average -> fp8 -> swizzled sZ write
__device__ __forceinline__ void consume(const uint2 (&gv)[KNB], unsigned mask, int cnt,
                                        int w, int lane, int s, unsigned char* sZ) {
    f32x2 a0 = {0.f, 0.f}, a1 = {0.f, 0.f}, a2 = {0.f, 0.f}, a3 = {0.f, 0.f};
    #pragma unroll
    for (int k = 0; k < KNB; ++k) {
        float mm = (float)((mask >> k) & 1u);
        f32x2 m2 = {mm, mm};
        a0 += m2 * cvt2_fp8<0>(gv[k].x);
        a1 += m2 * cvt2_fp8<1>(gv[k].x);
        a2 += m2 * cvt2_fp8<0>(gv[k].y);
        a3 += m2 * cvt2_fp8<1>(gv[k].y);
    }
    float sc = 1.0f / (float)(cnt > 0 ? cnt : 1);
    unsigned w0 = pk_fp8<0>(a0.x * sc, a0.y * sc, 0u);
    w0 = pk_fp8<1>(a1.x * sc, a1.y * sc, w0);
    unsigned w1 = pk_fp8<0>(a2.x * sc, a2.y * sc, 0u);
    w1 = pk_fp8<1>(a3.x * sc, a3.y * sc, w1);
    int rl = w * 8 + s * 2 + (lane >> 5);           // local row 0..63
    int gp = (lane & 31) ^ (rl & 7);
    *(uint2*)(sZ + rl * 256 + (gp << 3)) = make_uint2(w0, w1);
}

// ---- left step S (0..3): one barrier per step, stage-after-barrier dbuf
template <int S>
__device__ __forceinline__ void left_step(const u16* __restrict__ Zl,
                                          const u16* __restrict__ WT,
                                          const unsigned char* __restrict__ Z8,
                                          const int* __restrict__ n1,
                                          const int* __restrict__ n2,
                                          u16* sB0, u16* sB1, unsigned char* sZ,
                                          int m0, int t, int lane, int w, int wr, int wc,
                                          int2 (&icur)[5], unsigned& pmask, int& pcnt,
                                          uint2 (&gv)[KNB], f32x4 (&acc)[2][4]) {
    const int hi = lane >> 4, l15 = lane & 15;
    u16* sBcur = (S & 1) ? sB1 : sB0;
    u16* sBnxt = (S & 1) ? sB0 : sB1;
    // 1. A-frags of THIS step, global->VGPR (issued early, used ~500cy later)
    bf16x8 af[2][2];
    #pragma unroll
    for (int k2 = 0; k2 < 2; ++k2) {
        #pragma unroll
        for (int i = 0; i < 2; ++i) {
            int grow = m0 + wr * 32 + i * 16 + l15;
            if (grow >= MTOT) grow = MTOT - 1;
            af[k2][i] = *(const bf16x8*)(Zl + (size_t)grow * 256 + S * 64 + k2 * 32 + hi * 8);
        }
    }
    __builtin_amdgcn_sched_barrier(0);
    // 2. consume G(S-1): implicit vmcnt drains everything older incl. B(S) stage
    if (S > 0) consume(gv, pmask, pcnt, w, lane, S - 1, sZ);
    __builtin_amdgcn_sched_barrier(0);
    // 3. issue G(S)
    {
        int g = m0 + w * 8 + S * 2 + (lane >> 5);
        if (g >= MTOT) g = MTOT - 1;
        int p = (g >= NNODE);
        const unsigned char* zb = Z8 + (size_t)p * ((size_t)NNODE * 256) + ((lane & 31) << 3);
        unsigned mask = 0;
        int cnt = 0;
        #pragma unroll
        for (int k = 0; k < KNB; ++k) {
            int ix = (k & 1) ? icur[k >> 1].y : icur[k >> 1].x;
            int valid = (ix > -1) ? 1 : 0;
            mask |= (unsigned)valid << k;
            cnt += valid;
            gv[k] = *(const uint2*)(zb + (size_t)(valid ? ix : 0) * 256);
        }
        pmask = mask;
        pcnt = cnt;
    }
    __builtin_amdgcn_sched_barrier(0);
    // 4. idx(S+1)
    if (S < 3) {
        int g = m0 + w * 8 + (S + 1) * 2 + (lane >> 5);
        if (g >= MTOT) g = MTOT - 1;
        int p = (g >= NNODE);
        const int* nb = (p ? n2 : n1) + (size_t)(g - p * NNODE) * KNB;
        int2 inxt[5];
        #pragma unroll
        for (int q = 0; q < 5; ++q) inxt[q] = *(const int2*)(nb + 2 * q);
        #pragma unroll
        for (int q = 0; q < 5; ++q) icur[q] = inxt[q];
    }
    __builtin_amdgcn_sched_barrier(0);
    // 5. counted wait: keep {G(S)10 + idx(S+1)5}; drains B(S) stage + af(S)
    if (S < 3) asm volatile("s_waitcnt vmcnt(15)" ::: "memory");
    else       asm volatile("s_waitcnt vmcnt(10)" ::: "memory");
    __builtin_amdgcn_s_barrier();     // all waves: B(S) ready; all past MFMA(S-1)
    __builtin_amdgcn_sched_barrier(0);
    // 6. stage B(S+1) into the buffer MFMA(S-1) just finished with
    if (S < 3) stageBl(WT, sBnxt, (S + 1) * 64, t);
    // 7. MFMA(S)
    __builtin_amdgcn_s_setprio(1);
    #pragma unroll
    for (int k2 = 0; k2 < 2; ++k2) {
        int g = (k2 * 32 >> 3) + hi;                 // granule 0..7
        bf16x8 bfr[4];
        #pragma unroll
        for (int j = 0; j < 4; ++j) {
            int col = wc * 64 + j * 16 + l15;
            bfr[j] = *(const bf16x8*)((const char*)sBcur + col * 128 + ((g ^ (col & 7)) << 4));
        }
        #pragma unroll
        for (int i = 0; i < 2; ++i)
            #pragma unroll
            for (int j = 0; j < 4; ++j)
                acc[i][j] = __builtin_amdgcn_mfma_f32_16x16x32_bf16(af[k2][i], bfr[j], acc[i][j], 0, 0, 0);
    }
    __builtin_amdgcn_s_setprio(0);
}

// ---- kernel 2: FUSED gather + GEMM.
// BM=64, BN=256. 512 thr = 8 waves (2M x 4N), wave tile 32x64 -> acc[2][4].
// LDS 80KB: B dbuf 2x32K + sZ 16K -> 2 blocks/CU (VGPR-capped at 16 waves anyway).
// Left: 4 steps BK=64 bf16, ONE barrier/step, A-frags global. Right: 4 steps
// BK=64 fp8, zero barriers (az LDS, bz global L2-hot).
__global__ __launch_bounds__(512, 4) void gemm_fused(const u16* __restrict__ Zl,
                                                     const unsigned char* __restrict__ Z8,
                                                     const u16* __restrict__ WT,
                                                     const unsigned char* __restrict__ WT8,
                                                     const int* __restrict__ n1,
                                                     const int* __restrict__ n2,
                                                     float* __restrict__ C) {
    __shared__ u16 sB0[256 * 64];           // 32 KB
    __shared__ u16 sB1[256 * 64];           // 32 KB
    __shared__ unsigned char sZ[64 * 256];  // 16 KB fp8, 8B-granule XOR-swizzled
    // reversed block order: cast wrote high rows last -> first blocks hit L3/L2
    const int m0 = (1562 - blockIdx.x) * 64;
    const int t = threadIdx.x;
    const int lane = t & 63;
    const int w = t >> 6;
    const int wr = w >> 2, wc = w & 3;
    const int hi = lane >> 4, l15 = lane & 15;

    f32x4 acc[2][4] = {};
    uint2 gv[KNB];
    int2 icur[5];
    unsigned pmask = 0;
    int pcnt = 0;

    // prologue: stage B(0) + idx(0)
    stageBl(WT, sB0, 0, t);
    {
        int g = m0 + w * 8 + (lane >> 5);
        if (g >= MTOT) g = MTOT - 1;
        int p = (g >= NNODE);
        const int* nb = (p ? n2 : n1) + (size_t)(g - p * NNODE) * KNB;
        #pragma unroll
        for (int q = 0; q < 5; ++q) icur[q] = *(const int2*)(nb + 2 * q);
    }

    left_step<0>(Zl, WT, Z8, n1, n2, sB0, sB1, sZ, m0, t, lane, w, wr, wc, icur, pmask, pcnt, gv, acc);
    left_step<1>(Zl, WT, Z8, n1, n2, sB0, sB1, sZ, m0, t, lane, w, wr, wc, icur, pmask, pcnt, gv, acc);
    left_step<2>(Zl, WT, Z8, n1, n2, sB0, sB1, sZ, m0, t, lane, w, wr, wc, icur, pmask, pcnt, gv, acc);
    left_step<3>(Zl, WT, Z8, n1, n2, sB0, sB1, sZ, m0, t, lane, w, wr, wc, icur, pmask, pcnt, gv, acc);

    // final consume + single handoff sync (drains sZ ds_writes for all waves)
    consume(gv, pmask, pcnt, w, lane, 3, sZ);
    __syncthreads();

    // ---- right half: 4 steps of K=64, fp8 x fp8, no barriers
#define RSTEP(R)                                                              \
    do {                                                                      \
        __builtin_amdgcn_s_setprio(1);                                        \
        _Pragma("unroll")                                                     \
        for (int m = 0; m < 2; ++m) {                                         \
            long long az[2], bz[4];                                           \
            _Pragma("unroll")                                                 \
            for (int i = 0; i < 2; ++i) {                                     \
                int row = wr * 32 + i * 16 + l15;                             \
                int g8 = (R) * 8 + m * 4 + hi;                                \
                az[i] = *(const long long*)(sZ + row * 256 + ((g8 ^ (row & 7)) << 3)); \
            }                                                                 \
            _Pragma("unroll")                                                 \
            for (int j = 0; j < 4; ++j) {                                     \
                int col = wc * 64 + j * 16 + l15;                             \
                bz[j] = *(const long long*)(WT8 + (size_t)col * 256 + (R) * 64 + m * 32 + hi * 8); \
            }                                                                 \
            _Pragma("unroll")                                                 \
            for (int i = 0; i < 2; ++i)                                       \
                _Pragma("unroll")                                             \
                for (int j = 0; j < 4; ++j)                                   \
                    acc[i][j] = __builtin_amdgcn_mfma_f32_16x16x32_fp8_fp8(az[i], bz[j], acc[i][j], 0, 0, 0); \
        }                                                                     \
        __builtin_amdgcn_s_setprio(0);                                        \
    } while (0)

    RSTEP(0);
    RSTEP(1);
    RSTEP(2);
    RSTEP(3);
#undef RSTEP

    // ---- epilogue: relu + store (C/D layout: col = lane&15, row = (lane>>4)*4 + q)
    #pragma unroll
    for (int i = 0; i < 2; ++i) {
        int rbase = m0 + wr * 32 + i * 16 + (hi << 2);
        #pragma unroll
        for (int j = 0; j < 4; ++j) {
            int col = wc * 64 + j * 16 + l15;
            #pragma unroll
            for (int q = 0; q < 4; ++q) {
                int row = rbase + q;
                if (row < MTOT) C[(size_t)row * NF + col] = fmaxf(acc[i][j][q], 0.f);
            }
        }
    }
}

extern "C" void kernel_launch(void* const* d_in, const int* in_sizes, int n_in,
                              void* d_out, int out_size, void* d_ws, size_t ws_size,
                              hipStream_t stream) {
    const float* Z1  = (const float*)d_in[0];
    const float* Z2  = (const float*)d_in[1];
    const float* Wr  = (const float*)d_in[2];
    const float* Wnr = (const float*)d_in[3];
    const int*   n1  = (const int*)d_in[4];
    const int*   n2  = (const int*)d_in[5];
    float* out = (float*)d_out;

    u16* WT            = (u16*)d_ws;                              // 128 KB
    unsigned char* WT8 = (unsigned char*)d_ws + 131072;           // 64 KB
    u16* Zleft         = (u16*)((unsigned char*)d_ws + 196608);   // 51.2 MB
    unsigned char* Z8  = (unsigned char*)d_ws + 196608 + (size_t)MTOT * 512;  // 25.6 MB

    cast_all<<<13012, 256, 0, stream>>>(Z1, Z2, Wr, Wnr, Zleft, Z8, WT, WT8);
    gemm_fused<<<1563, 512, 0, stream>>>(Zleft, Z8, WT, WT8, n1, n2, out);
}

// Round 12
// 121.123 us; speedup vs baseline: 1.5867x; 1.5867x over previous
//
#include <hip/hip_runtime.h>
#include <hip/hip_bf16.h>
#include <hip/hip_fp8.h>

#define NNODE 50000
#define MTOT  100000   // 2*NNODE rows
#define NF    256
#define KNB   10

typedef unsigned short u16;
typedef float f32x4 __attribute__((ext_vector_type(4)));
typedef float f32x2 __attribute__((ext_vector_type(2)));
typedef short bf16x8 __attribute__((ext_vector_type(8)));

__device__ __forceinline__ u16 f2bf(float f) {
    unsigned u = __builtin_bit_cast(unsigned, f);
    unsigned r = (u + 0x7fffu + ((u >> 16) & 1u)) >> 16;
    return (u16)r;
}
__device__ __forceinline__ unsigned char f2f8(float f) {
    return (unsigned char)__hip_fp8_e4m3(f).__x;
}
__device__ __forceinline__ float f8tof(unsigned char b) {
    __hip_fp8_e4m3 h;
    h.__x = (__hip_fp8_storage_t)b;
    return (float)h;
}
template <int WORD>
__device__ __forceinline__ f32x2 cvt2_fp8(unsigned v) {
#if __has_builtin(__builtin_amdgcn_cvt_pk_f32_fp8)
    auto c = __builtin_amdgcn_cvt_pk_f32_fp8((int)v, WORD);
    f32x2 r; r.x = c[0]; r.y = c[1];
    return r;
#else
    unsigned s = WORD ? (v >> 16) : v;
    f32x2 r;
    r.x = f8tof((unsigned char)(s & 0xff));
    r.y = f8tof((unsigned char)((s >> 8) & 0xff));
    return r;
#endif
}
template <int WORD>
__device__ __forceinline__ unsigned pk_fp8(float a, float b, unsigned old) {
#if __has_builtin(__builtin_amdgcn_cvt_pk_fp8_f32)
    return (unsigned)__builtin_amdgcn_cvt_pk_fp8_f32(a, b, (int)old, WORD);
#else
    unsigned lo = (unsigned)f2f8(a) | ((unsigned)f2f8(b) << 8);
    return WORD ? ((old & 0x0000ffffu) | (lo << 16)) : ((old & 0xffff0000u) | lo);
#endif
}
__device__ __forceinline__ void gload_lds16(const void* g, void* l) {
    __builtin_amdgcn_global_load_lds(
        (const __attribute__((address_space(1))) unsigned int*)g,
        (__attribute__((address_space(3))) unsigned int*)l, 16, 0, 0);
}

// ---- kernel 1: merged cast (R9 verbatim, incl. WT8 half-bake).
__global__ __launch_bounds__(256) void cast_all(const float* __restrict__ Z1,
                                                const float* __restrict__ Z2,
                                                const float* __restrict__ Wr,
                                                const float* __restrict__ Wnr,
                                                u16* __restrict__ Zleft,
                                                unsigned char* __restrict__ Z8,
                                                u16* __restrict__ WT,
                                                unsigned char* __restrict__ WT8) {
    int b = blockIdx.x;
    if (b < 12500) {
        unsigned id = b * 256 + threadIdx.x;
        int m = id >> 5;
        int d = (id & 31) << 3;
        const float* src = (m < NNODE) ? (Z1 + (size_t)m * 256 + d)
                                       : (Z2 + (size_t)(m - NNODE) * 256 + d);
        float4 a = *(const float4*)src;
        float4 bb = *(const float4*)(src + 4);
        uint4 o;
        o.x = (unsigned)f2bf(a.x) | ((unsigned)f2bf(a.y) << 16);
        o.y = (unsigned)f2bf(a.z) | ((unsigned)f2bf(a.w) << 16);
        o.z = (unsigned)f2bf(bb.x) | ((unsigned)f2bf(bb.y) << 16);
        o.w = (unsigned)f2bf(bb.z) | ((unsigned)f2bf(bb.w) << 16);
        *(uint4*)(Zleft + (size_t)m * 256 + d) = o;
        uint2 o8;
        o8.x = (unsigned)f2f8(a.x) | ((unsigned)f2f8(a.y) << 8) |
               ((unsigned)f2f8(a.z) << 16) | ((unsigned)f2f8(a.w) << 24);
        o8.y = (unsigned)f2f8(bb.x) | ((unsigned)f2f8(bb.y) << 8) |
               ((unsigned)f2f8(bb.z) << 16) | ((unsigned)f2f8(bb.w) << 24);
        *(uint2*)(Z8 + (size_t)m * 256 + d) = o8;
    } else if (b < 12756) {
        int id = (b - 12500) * 256 + threadIdx.x;
        int n = id >> 8, k = id & 255;
        WT[n * 256 + k] = f2bf(Wr[(size_t)k * 256 + n]);
    } else {
        int id = (b - 12756) * 256 + threadIdx.x;
        int n = id >> 8, k = id & 255;
        int kb = k ^ (((n >> 2) & 1) << 3);          // bake: swap 8B halves per 16B
        WT8[n * 256 + kb] = f2f8(Wnr[(size_t)k * 256 + n]);
    }
}

// ---- staging: linear LDS dest + inverse-swizzled global source
__device__ __forceinline__ void stageA(const u16* __restrict__ Zl, u16* dst,
                                       int m0, int kt, int t) {
    // [64r][64k] bf16 = 512 granules of 16B, 1/thread, XOR row&7
    int row = t >> 3, gd = t & 7;
    int gs = gd ^ (row & 7);
    int grow = m0 + row;
    if (grow >= MTOT) grow = MTOT - 1;
    gload_lds16(Zl + (size_t)grow * 256 + kt + gs * 8, dst + t * 8);
}
__device__ __forceinline__ void stageBh(const u16* __restrict__ WT, u16* dst,
                                        int kt, int t) {
    // [256c][32k] bf16 half-tile = 1024 granules of 16B, 2/thread, XOR col&3
    #pragma unroll
    for (int rp = 0; rp < 2; ++rp) {
        int c = rp * 512 + t;
        int col = c >> 2, gd = c & 3;
        int gs = gd ^ (col & 3);
        gload_lds16(WT + (size_t)col * 256 + kt + gs * 8, dst + c * 8);
    }
}
__device__ __forceinline__ void stageBr(const unsigned char* __restrict__ WT8,
                                        unsigned char* dst, int ktr, int t) {
    // [256c][64k] fp8 = 1024 granules of 16B, 2/thread, XOR col&3 (half-bake in data)
    #pragma unroll
    for (int rp = 0; rp < 2; ++rp) {
        int c = rp * 512 + t;
        int col = c >> 2, gd = c & 3;
        int gs = gd ^ (col & 3);
        gload_lds16(WT8 + (size_t)col * 256 + ktr + gs * 16, dst + c * 16);
    }
}

// ---- consume gather packet of step s (R9 verbatim)
__device__ __forceinline__ void consume(const uint2 (&gv)[KNB], unsigned mask, int cnt,
                                        int w, int lane, int s, unsigned char* sZ) {
    f32x2 a0 = {0.f, 0.f}, a1 = {0.f, 0.f}, a2 = {0.f, 0.f}, a3 = {0.f, 0.f};
    #pragma unroll
    for (int k = 0; k < KNB; ++k) {
        float mm = (float)((mask >> k) & 1u);
        f32x2 m2 = {mm, mm};
        a0 += m2 * cvt2_fp8<0>(gv[k].x);
        a1 += m2 * cvt2_fp8<1>(gv[k].x);
        a2 += m2 * cvt2_fp8<0>(gv[k].y);
        a3 += m2 * cvt2_fp8<1>(gv[k].y);
    }
    float sc = 1.0f / (float)(cnt > 0 ? cnt : 1);
    unsigned w0 = pk_fp8<0>(a0.x * sc, a0.y * sc, 0u);
    w0 = pk_fp8<1>(a1.x * sc, a1.y * sc, w0);
    unsigned w1 = pk_fp8<0>(a2.x * sc, a2.y * sc, 0u);
    w1 = pk_fp8<1>(a3.x * sc, a3.y * sc, w1);
    int rl = w * 8 + s * 2 + (lane >> 5);           // local row 0..63
    int gp = (lane & 31) ^ (rl & 7);
    *(uint2*)(sZ + rl * 256 + (gp << 3)) = make_uint2(w0, w1);
}

// ---- one K=32 half of left MFMA
__device__ __forceinline__ void mfma_halfL(const u16* sAc, const u16* sBc, int k2,
                                           int lane, int wr, int wc, f32x4 (&acc)[2][4]) {
    const int hi = lane >> 4, l15 = lane & 15;
    bf16x8 af[2], bfr[4];
    #pragma unroll
    for (int i = 0; i < 2; ++i) {
        int row = wr * 32 + i * 16 + l15;
        af[i] = *(const bf16x8*)((const char*)sAc + row * 128 + (((k2 * 4 + hi) ^ (row & 7)) << 4));
    }
    #pragma unroll
    for (int j = 0; j < 4; ++j) {
        int col = wc * 64 + j * 16 + l15;
        bfr[j] = *(const bf16x8*)((const char*)sBc + col * 64 + ((hi ^ (col & 3)) << 4));
    }
    #pragma unroll
    for (int i = 0; i < 2; ++i)
        #pragma unroll
        for (int j = 0; j < 4; ++j)
            acc[i][j] = __builtin_amdgcn_mfma_f32_16x16x32_bf16(af[i], bfr[j], acc[i][j], 0, 0, 0);
}
// ---- right MFMA step (R9 verbatim, buffer passed in)
__device__ __forceinline__ void mfma_right(const unsigned char* sZ, const unsigned char* sBc,
                                           int R, int lane, int wr, int wc,
                                           f32x4 (&acc)[2][4]) {
    const int hi = lane >> 4, l15 = lane & 15;
    #pragma unroll
    for (int m = 0; m < 2; ++m) {
        long long az[2], bz[4];
        #pragma unroll
        for (int i = 0; i < 2; ++i) {
            int row = wr * 32 + i * 16 + l15;
            int g8 = R * 8 + m * 4 + hi;
            az[i] = *(const long long*)(sZ + row * 256 + ((g8 ^ (row & 7)) << 3));
        }
        #pragma unroll
        for (int j = 0; j < 4; ++j) {
            int col = wc * 64 + j * 16 + l15;
            int G = 2 * m + (hi >> 1);
            int hb = ((hi & 1) ^ ((col >> 2) & 1)) << 3;   // un-bake half select
            bz[j] = *(const long long*)(sBc + col * 64 + ((G ^ (col & 3)) << 4) + hb);
        }
        #pragma unroll
        for (int i = 0; i < 2; ++i)
            #pragma unroll
            for (int j = 0; j < 4; ++j)
                acc[i][j] = __builtin_amdgcn_mfma_f32_16x16x32_fp8_fp8(az[i], bz[j], acc[i][j], 0, 0, 0);
    }
}

// ---- kernel 2: FUSED gather + GEMM, 3-buffer B rotation at K=32 granularity.
// BM=64, BN=256. 512 thr = 8 waves (2M x 4N), wave tile 32x64 -> acc[2][4].
// LDS 80KB: sA 2x8K + sB 3x16K + sZ 16K -> 2 blocks/CU.
// Half-step u: vmcnt(counted) -> barrier -> stage(u+2) -> [h0: consume+gather] -> 8 MFMA.
// Race-free: stage at u targets sB[(u+2)%3], last read by mfma(u-1); all waves are
// past mfma(u-1) once past barrier(u). Every stage has 2 half-steps of slack.
__global__ __launch_bounds__(512, 4) void gemm_fused(const u16* __restrict__ Zl,
                                                     const unsigned char* __restrict__ Z8,
                                                     const u16* __restrict__ WT,
                                                     const unsigned char* __restrict__ WT8,
                                                     const int* __restrict__ n1,
                                                     const int* __restrict__ n2,
                                                     float* __restrict__ C) {
    __shared__ u16 sA[2][64 * 64];          // 2 x 8 KB
    __shared__ u16 sB[3][256 * 32];         // 3 x 16 KB (left bf16 halves; right fp8 64k tiles)
    __shared__ unsigned char sZ[64 * 256];  // 16 KB fp8, 8B-granule XOR-swizzled
    const int m0 = (1562 - blockIdx.x) * 64;   // reversed: first blocks hit L3-hot tail
    const int t = threadIdx.x;
    const int lane = t & 63;
    const int w = t >> 6;
    const int wr = w >> 2, wc = w & 3;
    const int hi = lane >> 4, l15 = lane & 15;

    f32x4 acc[2][4] = {};
    uint2 gv[KNB];
    int2 icur[5];
    unsigned pmask = 0;
    int pcnt = 0;

    // ---- prologue (issue order matters for vmcnt counts): idx(0), A(0), B(t0), B(t1)
    {
        int g = m0 + w * 8 + (lane >> 5);
        if (g >= MTOT) g = MTOT - 1;
        int p = (g >= NNODE);
        const int* nb = (p ? n2 : n1) + (size_t)(g - p * NNODE) * KNB;
        #pragma unroll
        for (int q = 0; q < 5; ++q) icur[q] = *(const int2*)(nb + 2 * q);
    }
    stageA(Zl, &sA[0][0], m0, 0, t);
    stageBh(WT, &sB[0][0], 0, t);
    stageBh(WT, &sB[1][0], 32, t);

    // ---- left half: macro-steps S=0..3, half-steps t_u = 2S+h
#define LH0(S)                                                                 \
    do {                                                                       \
        /* top wait: drain B(2S) + A(S); keep {B(2S+1)2, idx(S)5, G(S-1)10} */ \
        if ((S) == 0) asm volatile("s_waitcnt vmcnt(2)" ::: "memory");         \
        else          asm volatile("s_waitcnt vmcnt(17)" ::: "memory");        \
        __builtin_amdgcn_s_barrier();                                          \
        if ((S) < 3) stageBh(WT, &sB[(2 * (S) + 2) % 3][0], (2 * (S) + 2) * 32, t); \
        else         stageBr(WT8, (unsigned char*)&sB[2][0], 0, t);            \
        if ((S) < 3) stageA(Zl, &sA[((S) + 1) & 1][0], m0, ((S) + 1) * 64, t); \
        __builtin_amdgcn_sched_barrier(0);                                     \
        if ((S) > 0) consume(gv, pmask, pcnt, w, lane, (S) - 1, sZ);           \
        __builtin_amdgcn_sched_barrier(0);                                     \
        {   /* issue G(S) */                                                   \
            int g = m0 + w * 8 + (S) * 2 + (lane >> 5);                        \
            if (g >= MTOT) g = MTOT - 1;                                       \
            int p = (g >= NNODE);                                              \
            const unsigned char* zb = Z8 + (size_t)p * ((size_t)NNODE * 256) + ((lane & 31) << 3); \
            unsigned mask = 0;                                                 \
            int cnt = 0;                                                       \
            _Pragma("unroll")                                                  \
            for (int k = 0; k < KNB; ++k) {                                    \
                int ix = (k & 1) ? icur[k >> 1].y : icur[k >> 1].x;            \
                int valid = (ix > -1) ? 1 : 0;                                 \
                mask |= (unsigned)valid << k;                                  \
                cnt += valid;                                                  \
                gv[k] = *(const uint2*)(zb + (size_t)(valid ? ix : 0) * 256);  \
            }                                                                  \
            pmask = mask;                                                      \
            pcnt = cnt;                                                        \
        }                                                                      \
        if ((S) < 3) { /* idx(S+1) */                                          \
            int g = m0 + w * 8 + ((S) + 1) * 2 + (lane >> 5);                  \
            if (g >= MTOT) g = MTOT - 1;                                       \
            int p = (g >= NNODE);                                              \
            const int* nb = (p ? n2 : n1) + (size_t)(g - p * NNODE) * KNB;     \
            _Pragma("unroll")                                                  \
            for (int q = 0; q < 5; ++q) icur[q] = *(const int2*)(nb + 2 * q);  \
        }                                                                      \
        __builtin_amdgcn_sched_barrier(0);                                     \
        __builtin_amdgcn_s_setprio(1);                                         \
        mfma_halfL(&sA[(S) & 1][0], &sB[(2 * (S)) % 3][0], 0, lane, wr, wc, acc); \
        __builtin_amdgcn_s_setprio(0);                                         \
    } while (0)

#define LH1(S)                                                                 \
    do {                                                                       \
        /* drain B(2S+1); keep {B(2S+2)2, A(S+1)1, G(S)10, idx(S+1)5} */       \
        if ((S) < 3) asm volatile("s_waitcnt vmcnt(18)" ::: "memory");         \
        else         asm volatile("s_waitcnt vmcnt(12)" ::: "memory");         \
        __builtin_amdgcn_s_barrier();                                          \
        if ((S) < 3) stageBh(WT, &sB[(2 * (S) + 3) % 3][0], (2 * (S) + 3) * 32, t); \
        else         stageBr(WT8, (unsigned char*)&sB[0][0], 64, t);           \
        __builtin_amdgcn_sched_barrier(0);                                     \
        __builtin_amdgcn_s_setprio(1);                                         \
        mfma_halfL(&sA[(S) & 1][0], &sB[(2 * (S) + 1) % 3][0], 1, lane, wr, wc, acc); \
        __builtin_amdgcn_s_setprio(0);                                         \
    } while (0)

    LH0(0); LH1(0);
    LH0(1); LH1(1);
    LH0(2); LH1(2);
    LH0(3); LH1(3);
#undef LH0
#undef LH1

    // handoff: consume(3) (implicit vmcnt drains G(3)), sZ visible, merged R0 wait
    consume(gv, pmask, pcnt, w, lane, 3, sZ);
    asm volatile("s_waitcnt lgkmcnt(0)" ::: "memory");
    asm volatile("s_waitcnt vmcnt(2)" ::: "memory");   // drain Br(0); keep Br(1)
    __builtin_amdgcn_s_barrier();

    // ---- right half: R=0..3; mfma(R) reads sB[(8+R)%3] = {2,0,1,2}
#define RSTEP(R)                                                               \
    do {                                                                       \
        if ((R) > 0) {                                                         \
            if ((R) < 3) asm volatile("s_waitcnt vmcnt(2)" ::: "memory");      \
            else         asm volatile("s_waitcnt vmcnt(0)" ::: "memory");      \
            __builtin_amdgcn_s_barrier();                                      \
        }                                                                      \
        if ((R) < 2) stageBr(WT8, (unsigned char*)&sB[((R) + 10) % 3][0], ((R) + 2) * 64, t); \
        __builtin_amdgcn_s_setprio(1);                                         \
        mfma_right(sZ, (const unsigned char*)&sB[((R) + 8) % 3][0], (R), lane, wr, wc, acc); \
        __builtin_amdgcn_s_setprio(0);                                         \
    } while (0)

    RSTEP(0);
    RSTEP(1);
    RSTEP(2);
    RSTEP(3);
#undef RSTEP

    // ---- epilogue: relu + store (C/D layout: col = lane&15, row = (lane>>4)*4 + q)
    #pragma unroll
    for (int i = 0; i < 2; ++i) {
        int rbase = m0 + wr * 32 + i * 16 + (hi << 2);
        #pragma unroll
        for (int j = 0; j < 4; ++j) {
            int col = wc * 64 + j * 16 + l15;
            #pragma unroll
            for (int q = 0; q < 4; ++q) {
                int row = rbase + q;
                if (row < MTOT) C[(size_t)row * NF + col] = fmaxf(acc[i][j][q], 0.f);
            }
        }
    }
}

extern "C" void kernel_launch(void* const* d_in, const int* in_sizes, int n_in,
                              void* d_out, int out_size, void* d_ws, size_t ws_size,
                              hipStream_t stream) {
    const float* Z1  = (const float*)d_in[0];
    const float* Z2  = (const float*)d_in[1];
    const float* Wr  = (const float*)d_in[2];
    const float* Wnr = (const float*)d_in[3];
    const int*   n1  = (const int*)d_in[4];
    const int*   n2  = (const int*)d_in[5];
    float* out = (float*)d_out;

    u16* WT            = (u16*)d_ws;                              // 128 KB
    unsigned char* WT8 = (unsigned char*)d_ws + 131072;           // 64 KB
    u16* Zleft         = (u16*)((unsigned char*)d_ws + 196608);   // 51.2 MB
    unsigned char* Z8  = (unsigned char*)d_ws + 196608 + (size_t)MTOT * 512;  // 25.6 MB

    cast_all<<<13012, 256, 0, stream>>>(Z1, Z2, Wr, Wnr, Zleft, Z8, WT, WT8);
    gemm_fused<<<1563, 512, 0, stream>>>(Zleft, Z8, WT, WT8, n1, n2, out);
}

// Round 14
// 109.400 us; speedup vs baseline: 1.7567x; 1.1072x over previous
//
#include <hip/hip_runtime.h>
#include <hip/hip_bf16.h>
#include <hip/hip_fp8.h>

#define NNODE 50000
#define MTOT  100000   // 2*NNODE rows
#define NF    256
#define KNB   10

typedef unsigned short u16;
typedef float f32x4 __attribute__((ext_vector_type(4)));
typedef float f32x2 __attribute__((ext_vector_type(2)));
typedef short bf16x8 __attribute__((ext_vector_type(8)));

__device__ __forceinline__ u16 f2bf(float f) {
    unsigned u = __builtin_bit_cast(unsigned, f);
    unsigned r = (u + 0x7fffu + ((u >> 16) & 1u)) >> 16;
    return (u16)r;
}
__device__ __forceinline__ unsigned char f2f8(float f) {
    return (unsigned char)__hip_fp8_e4m3(f).__x;
}
__device__ __forceinline__ float f8tof(unsigned char b) {
    __hip_fp8_e4m3 h;
    h.__x = (__hip_fp8_storage_t)b;
    return (float)h;
}
template <int WORD>
__device__ __forceinline__ f32x2 cvt2_fp8(unsigned v) {
#if __has_builtin(__builtin_amdgcn_cvt_pk_f32_fp8)
    auto c = __builtin_amdgcn_cvt_pk_f32_fp8((int)v, WORD);
    f32x2 r; r.x = c[0]; r.y = c[1];
    return r;
#else
    unsigned s = WORD ? (v >> 16) : v;
    f32x2 r;
    r.x = f8tof((unsigned char)(s & 0xff));
    r.y = f8tof((unsigned char)((s >> 8) & 0xff));
    return r;
#endif
}
template <int WORD>
__device__ __forceinline__ unsigned pk_fp8(float a, float b, unsigned old) {
#if __has_builtin(__builtin_amdgcn_cvt_pk_fp8_f32)
    return (unsigned)__builtin_amdgcn_cvt_pk_fp8_f32(a, b, (int)old, WORD);
#else
    unsigned lo = (unsigned)f2f8(a) | ((unsigned)f2f8(b) << 8);
    return WORD ? ((old & 0x0000ffffu) | (lo << 16)) : ((old & 0xffff0000u) | lo);
#endif
}
__device__ __forceinline__ void gload_lds16(const void* g, void* l) {
    __builtin_amdgcn_global_load_lds(
        (const __attribute__((address_space(1))) unsigned int*)g,
        (__attribute__((address_space(3))) unsigned int*)l, 16, 0, 0);
}

// ---- kernel 1: merged cast.
//  [0,12500): Z -> bf16 Zleft + fp8 Z8
//  [12500,12756): WT bf16 [256 n][256 k] = Wr^T
//  [12756,13012): WT8 fp8 [256 n][256 k] = Wnr^T, 8B-halves of each 16B swapped
//                 when (n>>2)&1 (bank-spread bake for the right-B LDS reads)
__global__ __launch_bounds__(256) void cast_all(const float* __restrict__ Z1,
                                                const float* __restrict__ Z2,
                                                const float* __restrict__ Wr,
                                                const float* __restrict__ Wnr,
                                                u16* __restrict__ Zleft,
                                                unsigned char* __restrict__ Z8,
                                                u16* __restrict__ WT,
                                                unsigned char* __restrict__ WT8) {
    int b = blockIdx.x;
    if (b < 12500) {
        unsigned id = b * 256 + threadIdx.x;
        int m = id >> 5;
        int d = (id & 31) << 3;
        const float* src = (m < NNODE) ? (Z1 + (size_t)m * 256 + d)
                                       : (Z2 + (size_t)(m - NNODE) * 256 + d);
        float4 a = *(const float4*)src;
        float4 bb = *(const float4*)(src + 4);
        uint4 o;
        o.x = (unsigned)f2bf(a.x) | ((unsigned)f2bf(a.y) << 16);
        o.y = (unsigned)f2bf(a.z) | ((unsigned)f2bf(a.w) << 16);
        o.z = (unsigned)f2bf(bb.x) | ((unsigned)f2bf(bb.y) << 16);
        o.w = (unsigned)f2bf(bb.z) | ((unsigned)f2bf(bb.w) << 16);
        *(uint4*)(Zleft + (size_t)m * 256 + d) = o;
        uint2 o8;
        o8.x = (unsigned)f2f8(a.x) | ((unsigned)f2f8(a.y) << 8) |
               ((unsigned)f2f8(a.z) << 16) | ((unsigned)f2f8(a.w) << 24);
        o8.y = (unsigned)f2f8(bb.x) | ((unsigned)f2f8(bb.y) << 8) |
               ((unsigned)f2f8(bb.z) << 16) | ((unsigned)f2f8(bb.w) << 24);
        *(uint2*)(Z8 + (size_t)m * 256 + d) = o8;
    } else if (b < 12756) {
        int id = (b - 12500) * 256 + threadIdx.x;
        int n = id >> 8, k = id & 255;
        WT[n * 256 + k] = f2bf(Wr[(size_t)k * 256 + n]);
    } else {
        int id = (b - 12756) * 256 + threadIdx.x;
        int n = id >> 8, k = id & 255;
        int kb = k ^ (((n >> 2) & 1) << 3);          // bake: swap 8B halves per 16B
        WT8[n * 256 + kb] = f2f8(Wnr[(size_t)k * 256 + n]);
    }
}

// ---- staging: linear LDS dest + inverse-swizzled global source (16B granules)
__device__ __forceinline__ void stageA(const u16* __restrict__ Zl, u16* dst,
                                       int m0, int kt, int t) {
    // [64r][64k] bf16 = 512 granules, 1/thread, XOR row&7 (8 granules/row)
    int row = t >> 3, gd = t & 7;
    int gs = gd ^ (row & 7);
    int grow = m0 + row;
    if (grow >= MTOT) grow = MTOT - 1;
    gload_lds16(Zl + (size_t)grow * 256 + kt + gs * 8, dst + t * 8);
}
__device__ __forceinline__ void stageBl(const u16* __restrict__ WT, u16* dst,
                                        int kt, int t) {
    // [256c][64k] bf16 = 2048 granules, 4/thread, XOR col&7
    #pragma unroll
    for (int rp = 0; rp < 4; ++rp) {
        int c = rp * 512 + t;
        int col = c >> 3, gd = c & 7;
        int gs = gd ^ (col & 7);
        gload_lds16(WT + (size_t)col * 256 + kt + gs * 8, dst + c * 8);
    }
}
__device__ __forceinline__ void stageBr(const unsigned char* __restrict__ WT8,
                                        unsigned char* dst, int ktr, int t) {
    // [256c][64k] fp8 = 1024 granules, 2/thread, XOR col&3 (half-bake in data)
    #pragma unroll
    for (int rp = 0; rp < 2; ++rp) {
        int c = rp * 512 + t;
        int col = c >> 2, gd = c & 3;
        int gs = gd ^ (col & 3);
        gload_lds16(WT8 + (size_t)col * 256 + ktr + gs * 16, dst + c * 16);
    }
}

__device__ __forceinline__ void mfma_left(const u16* sAc, const u16* sBc, int lane,
                                          int wr, int wc, f32x4 (&acc)[2][4]) {
    const int hi = lane >> 4, l15 = lane & 15;
    #pragma unroll
    for (int kk = 0; kk < 64; kk += 32) {
        int g = (kk >> 3) + hi;                     // granule 0..7
        bf16x8 af[2], bfr[4];
        #pragma unroll
        for (int i = 0; i < 2; ++i) {
            int row = wr * 32 + i * 16 + l15;
            af[i] = *(const bf16x8*)((const char*)sAc + row * 128 + ((g ^ (row & 7)) << 4));
        }
        #pragma unroll
        for (int j = 0; j < 4; ++j) {
            int col = wc * 64 + j * 16 + l15;
            bfr[j] = *(const bf16x8*)((const char*)sBc + col * 128 + ((g ^ (col & 7)) << 4));
        }
        #pragma unroll
        for (int i = 0; i < 2; ++i)
            #pragma unroll
            for (int j = 0; j < 4; ++j)
                acc[i][j] = __builtin_amdgcn_mfma_f32_16x16x32_bf16(af[i], bfr[j], acc[i][j], 0, 0, 0);
    }
}
__device__ __forceinline__ void mfma_right(const unsigned char* sZ, const unsigned char* sBc,
                                           int R, int lane, int wr, int wc,
                                           f32x4 (&acc)[2][4]) {
    const int hi = lane >> 4, l15 = lane & 15;
    #pragma unroll
    for (int m = 0; m < 2; ++m) {
        long long az[2], bz[4];
        #pragma unroll
        for (int i = 0; i < 2; ++i) {
            int row = wr * 32 + i * 16 + l15;
            int g8 = R * 8 + m * 4 + hi;            // 8B granule 0..31
            az[i] = *(const long long*)(sZ + row * 256 + ((g8 ^ (row & 7)) << 3));
        }
        #pragma unroll
        for (int j = 0; j < 4; ++j) {
            int col = wc * 64 + j * 16 + l15;
            int G = 2 * m + (hi >> 1);              // 16B granule 0..3
            int hb = ((hi & 1) ^ ((col >> 2) & 1)) << 3;   // un-bake half select
            bz[j] = *(const long long*)(sBc + col * 64 + ((G ^ (col & 3)) << 4) + hb);
        }
        #pragma unroll
        for (int i = 0; i < 2; ++i)
            #pragma unroll
            for (int j = 0; j < 4; ++j)
                acc[i][j] = __builtin_amdgcn_mfma_f32_16x16x32_fp8_fp8(az[i], bz[j], acc[i][j], 0, 0, 0);
    }
}

// ---- consume gather packet of step s: average -> fp8 -> swizzled sZ write
__device__ __forceinline__ void consume(const uint2 (&gv)[KNB], unsigned mask, int cnt,
                                        int w, int lane, int s, unsigned char* sZ) {
    f32x2 a0 = {0.f, 0.f}, a1 = {0.f, 0.f}, a2 = {0.f, 0.f}, a3 = {0.f, 0.f};
    #pragma unroll
    for (int k = 0; k < KNB; ++k) {
        float mm = (float)((mask >> k) & 1u);
        f32x2 m2 = {mm, mm};
        a0 += m2 * cvt2_fp8<0>(gv[k].x);
        a1 += m2 * cvt2_fp8<1>(gv[k].x);
        a2 += m2 * cvt2_fp8<0>(gv[k].y);
        a3 += m2 * cvt2_fp8<1>(gv[k].y);
    }
    float sc = 1.0f / (float)(cnt > 0 ? cnt : 1);
    unsigned w0 = pk_fp8<0>(a0.x * sc, a0.y * sc, 0u);
    w0 = pk_fp8<1>(a1.x * sc, a1.y * sc, w0);
    unsigned w1 = pk_fp8<0>(a2.x * sc, a2.y * sc, 0u);
    w1 = pk_fp8<1>(a3.x * sc, a3.y * sc, w1);
    int rl = w * 8 + s * 2 + (lane >> 5);           // local row 0..63
    int gp = (lane & 31) ^ (rl & 7);
    *(uint2*)(sZ + rl * 256 + (gp << 3)) = make_uint2(w0, w1);
}

// ---- left step S (0..3): pinned issue order + counted vmcnt.
// TWO barriers per step, both load-bearing: the pre-MFMA barrier publishes the
// staged B(S)/A tiles; the TRAILING barrier keeps any wave from staging B(S+1)
// over the single sBL buffer while another wave still MFMA-reads B(S).
// (R13 dropped the trailing barrier -> absmax 36 data race. Do not remove.)
template <int S>
__device__ __forceinline__ void left_step(const u16* __restrict__ Zl,
                                          const u16* __restrict__ WT,
                                          const unsigned char* __restrict__ Z8,
                                          const int* __restrict__ n1,
                                          const int* __restrict__ n2,
                                          u16* sA0, u16* sA1, u16* sBL, unsigned char* sZ,
                                          int m0, int t, int lane, int w, int wr, int wc,
                                          int2 (&icur)[5], unsigned& pmask, int& pcnt,
                                          uint2 (&gv)[KNB], f32x4 (&acc)[2][4]) {
    u16* sAcur = (S & 1) ? sA1 : sA0;
    u16* sAnxt = (S & 1) ? sA0 : sA1;
    // 1. B(S) [4 gloads]
    stageBl(WT, sBL, S * 64, t);
    __builtin_amdgcn_sched_barrier(0);
    // 2. A(S+1) [1 gload]
    if (S < 3) stageA(Zl, sAnxt, m0, (S + 1) * 64, t);
    __builtin_amdgcn_sched_barrier(0);
    // 3. idx(S+1) [5 dwordx2]
    int2 inxt[5];
    if (S < 3) {
        int rl = w * 8 + (S + 1) * 2 + (lane >> 5);
        int g = m0 + rl;
        if (g >= MTOT) g = MTOT - 1;
        int p = (g >= NNODE);
        const int* nb = (p ? n2 : n1) + (size_t)(g - p * NNODE) * KNB;
        #pragma unroll
        for (int q = 0; q < 5; ++q) inxt[q] = *(const int2*)(nb + 2 * q);
    }
    __builtin_amdgcn_sched_barrier(0);
    // 4. consume G(S-1) (auto-wait leaves this step's issues in flight)
    if (S > 0) consume(gv, pmask, pcnt, w, lane, S - 1, sZ);
    __builtin_amdgcn_sched_barrier(0);
    // 5. issue G(S) [10 dwordx2] using icur; derive mask/cnt; rotate idx
    {
        int g = m0 + w * 8 + S * 2 + (lane >> 5);
        if (g >= MTOT) g = MTOT - 1;
        int p = (g >= NNODE);
        const unsigned char* zb = Z8 + (size_t)p * ((size_t)NNODE * 256) + ((lane & 31) << 3);
        unsigned mask = 0;
        int cnt = 0;
        #pragma unroll
        for (int k = 0; k < KNB; ++k) {
            int ix = (k & 1) ? icur[k >> 1].y : icur[k >> 1].x;
            int valid = (ix > -1) ? 1 : 0;
            mask |= (unsigned)valid << k;
            cnt += valid;
            gv[k] = *(const uint2*)(zb + (size_t)(valid ? ix : 0) * 256);
        }
        pmask = mask;
        pcnt = cnt;
    }
    if (S < 3) {
        #pragma unroll
        for (int q = 0; q < 5; ++q) icur[q] = inxt[q];
    }
    __builtin_amdgcn_sched_barrier(0);
    // 6. counted wait: keep {A(S+1)1, idx5, G10}=16 (S<3) / {G10} (S=3); drains B(S)
    if (S < 3) asm volatile("s_waitcnt vmcnt(16)" ::: "memory");
    else       asm volatile("s_waitcnt vmcnt(10)" ::: "memory");
    __builtin_amdgcn_s_barrier();
    __builtin_amdgcn_s_setprio(1);
    mfma_left(sAcur, sBL, lane, wr, wc, acc);
    __builtin_amdgcn_s_setprio(0);
    __builtin_amdgcn_s_barrier();   // trailing barrier: protects sBL reuse (load-bearing!)
}

// ---- kernel 2: FUSED gather + GEMM. BM=64, BN=256. 64KB LDS -> 2 blocks/CU.
// 512 thr = 8 waves (2M x 4N), wave tile 32x64 -> acc[2][4] (32 regs).
// Left: 4 steps BK=64 bf16 (A dbuf, B single). Right: 4 steps BK=64 fp8 (B dbuf in sB).
__global__ __launch_bounds__(512, 4) void gemm_fused(const u16* __restrict__ Zl,
                                                     const unsigned char* __restrict__ Z8,
                                                     const u16* __restrict__ WT,
                                                     const unsigned char* __restrict__ WT8,
                                                     const int* __restrict__ n1,
                                                     const int* __restrict__ n2,
                                                     float* __restrict__ C) {
    __shared__ char smem[65536];
    u16* sA0 = (u16*)smem;                               //  8 KB
    u16* sA1 = (u16*)(smem + 8192);                      //  8 KB
    u16* sBL = (u16*)(smem + 16384);                     // 32 KB (left B)
    unsigned char* sBr0 = (unsigned char*)(smem + 16384);// right chunk 0 (16 KB)
    unsigned char* sBr1 = (unsigned char*)(smem + 32768);// right chunk 1 (16 KB)
    unsigned char* sZ = (unsigned char*)(smem + 49152);  // 16 KB fp8 Zavg

    const int m0 = blockIdx.x * 64;
    const int t = threadIdx.x;
    const int lane = t & 63;
    const int w = t >> 6;
    const int wr = w >> 2, wc = w & 3;

    f32x4 acc[2][4] = {};
    uint2 gv[KNB];
    int2 icur[5];
    unsigned pmask = 0;
    int pcnt = 0;

    // prologue: A(0) + idx(0)
    stageA(Zl, sA0, m0, 0, t);
    {
        int g = m0 + w * 8 + (lane >> 5);
        if (g >= MTOT) g = MTOT - 1;
        int p = (g >= NNODE);
        const int* nb = (p ? n2 : n1) + (size_t)(g - p * NNODE) * KNB;
        #pragma unroll
        for (int q = 0; q < 5; ++q) icur[q] = *(const int2*)(nb + 2 * q);
    }

    left_step<0>(Zl, WT, Z8, n1, n2, sA0, sA1, sBL, sZ, m0, t, lane, w, wr, wc, icur, pmask, pcnt, gv, acc);
    left_step<1>(Zl, WT, Z8, n1, n2, sA0, sA1, sBL, sZ, m0, t, lane, w, wr, wc, icur, pmask, pcnt, gv, acc);
    left_step<2>(Zl, WT, Z8, n1, n2, sA0, sA1, sBL, sZ, m0, t, lane, w, wr, wc, icur, pmask, pcnt, gv, acc);
    left_step<3>(Zl, WT, Z8, n1, n2, sA0, sA1, sBL, sZ, m0, t, lane, w, wr, wc, icur, pmask, pcnt, gv, acc);

    // right entry: final consume, stage chunk 0, full drain, sync
    consume(gv, pmask, pcnt, w, lane, 3, sZ);
    stageBr(WT8, sBr0, 0, t);
    asm volatile("s_waitcnt vmcnt(0)" ::: "memory");
    asm volatile("s_waitcnt lgkmcnt(0)" ::: "memory");
    __builtin_amdgcn_s_barrier();

#define RSTEP(R)                                                            \
    do {                                                                    \
        if ((R) < 3) {                                                      \
            stageBr(WT8, ((R) & 1) ? sBr0 : sBr1, ((R) + 1) * 64, t);       \
            asm volatile("s_waitcnt vmcnt(2)" ::: "memory");                \
        } else {                                                            \
            asm volatile("s_waitcnt vmcnt(0)" ::: "memory");                \
        }                                                                   \
        __builtin_amdgcn_s_barrier();                                       \
        __builtin_amdgcn_s_setprio(1);                                      \
        mfma_right(sZ, ((R) & 1) ? sBr1 : sBr0, (R), lane, wr, wc, acc);    \
        __builtin_amdgcn_s_setprio(0);                                      \
        if ((R) < 3) __builtin_amdgcn_s_barrier();                          \
    } while (0)

    RSTEP(0);
    RSTEP(1);
    RSTEP(2);
    RSTEP(3);
#undef RSTEP

    // epilogue: relu + store (C/D layout: col = lane&15, row = (lane>>4)*4 + q)
    const int l15 = lane & 15;
    const int hi = lane >> 4;
    #pragma unroll
    for (int i = 0; i < 2; ++i) {
        int rbase = m0 + wr * 32 + i * 16 + (hi << 2);
        #pragma unroll
        for (int j = 0; j < 4; ++j) {
            int col = wc * 64 + j * 16 + l15;
            #pragma unroll
            for (int q = 0; q < 4; ++q) {
                int row = rbase + q;
                if (row < MTOT) C[(size_t)row * NF + col] = fmaxf(acc[i][j][q], 0.f);
            }
        }
    }
}

extern "C" void kernel_launch(void* const* d_in, const int* in_sizes, int n_in,
                              void* d_out, int out_size, void* d_ws, size_t ws_size,
                              hipStream_t stream) {
    const float* Z1  = (const float*)d_in[0];
    const float* Z2  = (const float*)d_in[1];
    const float* Wr  = (const float*)d_in[2];
    const float* Wnr = (const float*)d_in[3];
    const int*   n1  = (const int*)d_in[4];
    const int*   n2  = (const int*)d_in[5];
    float* out = (float*)d_out;

    u16* WT            = (u16*)d_ws;                              // 128 KB
    unsigned char* WT8 = (unsigned char*)d_ws + 131072;           // 64 KB
    u16* Zleft         = (u16*)((unsigned char*)d_ws + 196608);   // 51.2 MB
    unsigned char* Z8  = (unsigned char*)d_ws + 196608 + (size_t)MTOT * 512;  // 25.6 MB

    cast_all<<<13012, 256, 0, stream>>>(Z1, Z2, Wr, Wnr, Zleft, Z8, WT, WT8);
    gemm_fused<<<1563, 512, 0, stream>>>(Zleft, Z8, WT, WT8, n1, n2, out);
}